// Round 3
// baseline (78.055 us; speedup 1.0000x reference)
//
#include <hip/hip_runtime.h>

#define NPAT 90

namespace {

constexpr const char* PB[NPAT] = {
    "1100110000110011","1100101001010011","1100101000110101","1100100101100011","1100100100110110",
    "1100011010010011","1100011000111001","1100010110100011","1100010100111010","1100001111000011",
    "1100001110100101","1100001110010110","1100001101101001","1100001101011010","1100001100111100",
    "1010110001010011","1010110000110101","1010101001010101","1010100101100101","1010100101010110",
    "1010011010010101","1010011001011001","1010010111000011","1010010110100101","1010010110010110",
    "1010010101101001","1010010101011010","1010010100111100","1010001111000101","1010001101011100",
    "1001110001100011","1001110000110110","1001101001100101","1001101001010110","1001100101100110",
    "1001011011000011","1001011010100101","1001011010010110","1001011001101001","1001011001011010",
    "1001011000111100","1001010110100110","1001010101101010","1001001111000110","1001001101101100",
    "0110110010010011","0110110000111001","0110101010010101","0110101001011001","0110100111000011",
    "0110100110100101","0110100110010110","0110100101101001","0110100101011010","0110100100111100",
    "0110011010011001","0110010110101001","0110010110011010","0110001111001001","0110001110011100",
    "0101110010100011","0101110000111010","0101101011000011","0101101010100101","0101101010010110",
    "0101101001101001","0101101001011010","0101101000111100","0101100110100110","0101100101101010",
    "0101011010101001","0101011010011010","0101010110101010","0101001111001010","0101001110101100",
    "0011110011000011","0011110010100101","0011110010010110","0011110001101001","0011110001011010",
    "0011110000111100","0011101011000101","0011101001011100","0011100111000110","0011100101101100",
    "0011011011001001","0011011010011100","0011010111001010","0011010110101100","0011001111001100",
};

// mask bit e set iff element e (row-major in 4x4 tile) is kept
constexpr unsigned short mask_of(int p) {
    unsigned m = 0;
    for (int e = 0; e < 16; ++e)
        if (PB[p][e] == '1') m |= (1u << e);
    return (unsigned short)m;
}

// For COLUMN c of pattern p: the two set rows (r1<r2) -> pair index
// (0,1)->0 (0,2)->1 (0,3)->2 (1,2)->3 (1,3)->4 (2,3)->5
constexpr unsigned char colpair_of(int p, int c) {
    int a = -1, b = -1;
    for (int r = 0; r < 4; ++r)
        if (PB[p][4 * r + c] == '1') { if (a < 0) a = r; else b = r; }
    return (unsigned char)(a == 0 ? (b - 1) : (a == 1 ? (b + 1) : 5));
}

struct PTab {
    unsigned short mask[NPAT];
    unsigned char  pc[NPAT][4];
};

constexpr PTab make_tab() {
    PTab t{};
    for (int p = 0; p < NPAT; ++p) {
        t.mask[p] = mask_of(p);
        for (int c = 0; c < 4; ++c) t.pc[p][c] = colpair_of(p, c);
    }
    return t;
}

constexpr PTab TAB = make_tab();

} // namespace

// 6 pairwise f32 sums of one COLUMN's 4 abs-values. Each is a single f32
// add of two f32 values -> exact rounding, operand-order independent.
__device__ __forceinline__ void colsums(float a0, float a1, float a2, float a3, float* q) {
    q[0] = a0 + a1; q[1] = a0 + a2; q[2] = a0 + a3;
    q[3] = a1 + a2; q[4] = a1 + a3; q[5] = a2 + a3;
}

__device__ __forceinline__ void emit(const float4 v, unsigned nib, float* op, float* mp) {
    float4 o, q;
    o.x = (nib & 1) ? v.x : 0.0f;  q.x = (nib & 1) ? 1.0f : 0.0f;
    o.y = (nib & 2) ? v.y : 0.0f;  q.y = (nib & 2) ? 1.0f : 0.0f;
    o.z = (nib & 4) ? v.z : 0.0f;  q.z = (nib & 4) ? 1.0f : 0.0f;
    o.w = (nib & 8) ? v.w : 0.0f;  q.w = (nib & 8) ? 1.0f : 0.0f;
    *(float4*)op = o;
    *(float4*)mp = q;
}

__global__ __launch_bounds__(256) void TransposableSparse_71932112273438_kernel(
        const float* __restrict__ x, float* __restrict__ sp, float* __restrict__ mf) {
    constexpr int K  = 8192;
    constexpr int KT = K / 4;   // 2048 tiles per row band (power of two)

    const int t = blockIdx.x * 256 + threadIdx.x;
    const int i = t >> 11;          // t / KT
    const int j = t & (KT - 1);     // t % KT

    const size_t off = (size_t)(i * 4) * K + (size_t)j * 4;
    const float* xp = x + off;

    const float4 v0 = *(const float4*)(xp);
    const float4 v1 = *(const float4*)(xp + K);
    const float4 v2 = *(const float4*)(xp + 2 * K);
    const float4 v3 = *(const float4*)(xp + 3 * K);

    // Column-wise pair sums (numpy einsum SIMD lanes: lane j holds the f32
    // sum of the two selected |x| in column j — exact single add in every
    // SIMD-width variant).
    float cp[4][6];
    colsums(fabsf(v0.x), fabsf(v1.x), fabsf(v2.x), fabsf(v3.x), cp[0]);
    colsums(fabsf(v0.y), fabsf(v1.y), fabsf(v2.y), fabsf(v3.y), cp[1]);
    colsums(fabsf(v0.z), fabsf(v1.z), fabsf(v2.z), fabsf(v3.z), cp[2]);
    colsums(fabsf(v0.w), fabsf(v1.w), fabsf(v2.w), fabsf(v3.w), cp[3]);

    // Horizontal-sum order: (c0+c2)+(c1+c3) — matches numpy npyv_sum_f32 on
    // AVX512 (_mm512_reduce_add_ps AND the non-reduce fallback) and on
    // SSE2-without-SSE3 (movehl fold). Strict '>' keeps the FIRST maximum,
    // matching np.argmax.
    float best = -1.0f;
    unsigned mbest = 0;
#pragma unroll
    for (int p = 0; p < NPAT; ++p) {
        const float s02 = cp[0][TAB.pc[p][0]] + cp[2][TAB.pc[p][2]];
        const float s13 = cp[1][TAB.pc[p][1]] + cp[3][TAB.pc[p][3]];
        const float s = s02 + s13;
        const bool c = s > best;
        best  = c ? s : best;
        mbest = c ? (unsigned)TAB.mask[p] : mbest;
    }

    float* spo = sp + off;
    float* mfo = mf + off;
    emit(v0, (mbest      ) & 0xF, spo,         mfo);
    emit(v1, (mbest >>  4) & 0xF, spo + K,     mfo + K);
    emit(v2, (mbest >>  8) & 0xF, spo + 2 * K, mfo + 2 * K);
    emit(v3, (mbest >> 12) & 0xF, spo + 3 * K, mfo + 3 * K);
}

extern "C" void kernel_launch(void* const* d_in, const int* in_sizes, int n_in,
                              void* d_out, int out_size, void* d_ws, size_t ws_size,
                              hipStream_t stream) {
    constexpr int M = 4096, K = 8192;
    constexpr int T = (M / 4) * (K / 4);   // 2,097,152 tiles

    const float* x  = (const float*)d_in[0];
    float* sparse   = (float*)d_out;
    float* maskout  = sparse + (size_t)M * K;

    dim3 grid(T / 256), block(256);
    hipLaunchKernelGGL(TransposableSparse_71932112273438_kernel,
                       grid, block, 0, stream, x, sparse, maskout);
}

// Round 5
// 71.612 us; speedup vs baseline: 1.0900x; 1.0900x over previous
//
#include <hip/hip_runtime.h>

#define NPAT 90

typedef float f32x4 __attribute__((ext_vector_type(4)));

namespace {

constexpr const char* PB[NPAT] = {
    "1100110000110011","1100101001010011","1100101000110101","1100100101100011","1100100100110110",
    "1100011010010011","1100011000111001","1100010110100011","1100010100111010","1100001111000011",
    "1100001110100101","1100001110010110","1100001101101001","1100001101011010","1100001100111100",
    "1010110001010011","1010110000110101","1010101001010101","1010100101100101","1010100101010110",
    "1010011010010101","1010011001011001","1010010111000011","1010010110100101","1010010110010110",
    "1010010101101001","1010010101011010","1010010100111100","1010001111000101","1010001101011100",
    "1001110001100011","1001110000110110","1001101001100101","1001101001010110","1001100101100110",
    "1001011011000011","1001011010100101","1001011010010110","1001011001101001","1001011001011010",
    "1001011000111100","1001010110100110","1001010101101010","1001001111000110","1001001101101100",
    "0110110010010011","0110110000111001","0110101010010101","0110101001011001","0110100111000011",
    "0110100110100101","0110100110010110","0110100101101001","0110100101011010","0110100100111100",
    "0110011010011001","0110010110101001","0110010110011010","0110001111001001","0110001110011100",
    "0101110010100011","0101110000111010","0101101011000011","0101101010100101","0101101010010110",
    "0101101001101001","0101101001011010","0101101000111100","0101100110100110","0101100101101010",
    "0101011010101001","0101011010011010","0101010110101010","0101001111001010","0101001110101100",
    "0011110011000011","0011110010100101","0011110010010110","0011110001101001","0011110001011010",
    "0011110000111100","0011101011000101","0011101001011100","0011100111000110","0011100101101100",
    "0011011011001001","0011011010011100","0011010111001010","0011010110101100","0011001111001100",
};

// mask bit e set iff element e (row-major in 4x4 tile) is kept
constexpr unsigned short mask_of(int p) {
    unsigned m = 0;
    for (int e = 0; e < 16; ++e)
        if (PB[p][e] == '1') m |= (1u << e);
    return (unsigned short)m;
}

// For COLUMN c of pattern p: the two set rows (r1<r2) -> pair index
// (0,1)->0 (0,2)->1 (0,3)->2 (1,2)->3 (1,3)->4 (2,3)->5
constexpr unsigned char colpair_of(int p, int c) {
    int a = -1, b = -1;
    for (int r = 0; r < 4; ++r)
        if (PB[p][4 * r + c] == '1') { if (a < 0) a = r; else b = r; }
    return (unsigned char)(a == 0 ? (b - 1) : (a == 1 ? (b + 1) : 5));
}

struct PTab {
    unsigned short mask[NPAT];
    unsigned char  pc[NPAT][4];
};

constexpr PTab make_tab() {
    PTab t{};
    for (int p = 0; p < NPAT; ++p) {
        t.mask[p] = mask_of(p);
        for (int c = 0; c < 4; ++c) t.pc[p][c] = colpair_of(p, c);
    }
    return t;
}

constexpr PTab TAB = make_tab();

} // namespace

// 6 pairwise f32 sums of one COLUMN's 4 abs-values. Each is a single f32
// add of two f32 values -> exact rounding, operand-order independent.
__device__ __forceinline__ void colsums(float a0, float a1, float a2, float a3, float* q) {
    q[0] = a0 + a1; q[1] = a0 + a2; q[2] = a0 + a3;
    q[3] = a1 + a2; q[4] = a1 + a3; q[5] = a2 + a3;
}

__device__ __forceinline__ void emit(const f32x4 v, unsigned nib, float* op, float* mp) {
    f32x4 o, q;
    o[0] = (nib & 1) ? v[0] : 0.0f;  q[0] = (nib & 1) ? 1.0f : 0.0f;
    o[1] = (nib & 2) ? v[1] : 0.0f;  q[1] = (nib & 2) ? 1.0f : 0.0f;
    o[2] = (nib & 4) ? v[2] : 0.0f;  q[2] = (nib & 4) ? 1.0f : 0.0f;
    o[3] = (nib & 8) ? v[3] : 0.0f;  q[3] = (nib & 8) ? 1.0f : 0.0f;
    __builtin_nontemporal_store(o, (f32x4*)op);
    __builtin_nontemporal_store(q, (f32x4*)mp);
}

__global__ __launch_bounds__(256) void TransposableSparse_71932112273438_kernel(
        const float* __restrict__ x, float* __restrict__ sp, float* __restrict__ mf) {
    constexpr int K  = 8192;
    constexpr int KT = K / 4;   // 2048 tiles per row band (power of two)

    const int t = blockIdx.x * 256 + threadIdx.x;
    const int i = t >> 11;          // t / KT
    const int j = t & (KT - 1);     // t % KT

    const size_t off = (size_t)(i * 4) * K + (size_t)j * 4;
    const float* xp = x + off;

    // Streaming data with zero reuse: nontemporal loads/stores keep the
    // 400 MB of traffic from churning L1/L2 (nt flag on global ops).
    const f32x4 v0 = __builtin_nontemporal_load((const f32x4*)(xp));
    const f32x4 v1 = __builtin_nontemporal_load((const f32x4*)(xp + K));
    const f32x4 v2 = __builtin_nontemporal_load((const f32x4*)(xp + 2 * K));
    const f32x4 v3 = __builtin_nontemporal_load((const f32x4*)(xp + 3 * K));

    // Column-wise pair sums (numpy einsum SIMD lanes: lane j holds the f32
    // sum of the two selected |x| in column j — exact single add in every
    // SIMD-width variant).
    float cp[4][6];
    colsums(fabsf(v0[0]), fabsf(v1[0]), fabsf(v2[0]), fabsf(v3[0]), cp[0]);
    colsums(fabsf(v0[1]), fabsf(v1[1]), fabsf(v2[1]), fabsf(v3[1]), cp[1]);
    colsums(fabsf(v0[2]), fabsf(v1[2]), fabsf(v2[2]), fabsf(v3[2]), cp[2]);
    colsums(fabsf(v0[3]), fabsf(v1[3]), fabsf(v2[3]), fabsf(v3[3]), cp[3]);

    // Horizontal-sum order: (c0+c2)+(c1+c3) — matches numpy npyv_sum_f32
    // (verified bit-exact in round 3: absmax == 0.0). Strict '>' keeps the
    // FIRST maximum, matching np.argmax. DO NOT change this association.
    float best = -1.0f;
    unsigned mbest = 0;
#pragma unroll
    for (int p = 0; p < NPAT; ++p) {
        const float s02 = cp[0][TAB.pc[p][0]] + cp[2][TAB.pc[p][2]];
        const float s13 = cp[1][TAB.pc[p][1]] + cp[3][TAB.pc[p][3]];
        const float s = s02 + s13;
        const bool c = s > best;
        best  = c ? s : best;
        mbest = c ? (unsigned)TAB.mask[p] : mbest;
    }

    float* spo = sp + off;
    float* mfo = mf + off;
    emit(v0, (mbest      ) & 0xF, spo,         mfo);
    emit(v1, (mbest >>  4) & 0xF, spo + K,     mfo + K);
    emit(v2, (mbest >>  8) & 0xF, spo + 2 * K, mfo + 2 * K);
    emit(v3, (mbest >> 12) & 0xF, spo + 3 * K, mfo + 3 * K);
}

extern "C" void kernel_launch(void* const* d_in, const int* in_sizes, int n_in,
                              void* d_out, int out_size, void* d_ws, size_t ws_size,
                              hipStream_t stream) {
    constexpr int M = 4096, K = 8192;
    constexpr int T = (M / 4) * (K / 4);   // 2,097,152 tiles

    const float* x  = (const float*)d_in[0];
    float* sparse   = (float*)d_out;
    float* maskout  = sparse + (size_t)M * K;

    dim3 grid(T / 256), block(256);
    hipLaunchKernelGGL(TransposableSparse_71932112273438_kernel,
                       grid, block, 0, stream, x, sparse, maskout);
}